// Round 1
// baseline (128.650 us; speedup 1.0000x reference)
//
#include <hip/hip_runtime.h>

// MLP: 64 × (Linear(5,5) + ReLU) then Linear(5,1), BATCH = 1048576 rows.
// Compute-bound on fp32 VALU (no fp32 MFMA on CDNA4). One thread per row;
// h[5] lives in VGPRs; weights are wave-uniform loads from read-only global
// -> scalar (s_load) pipe, feeding v_fma_f32 as the single SGPR operand.

#define MLP_DEPTH 64
#define MLP_D 5

__global__ __launch_bounds__(256) void MLP_89687507075104_kernel(
    const float* __restrict__ x,      // [n, 5]
    const float* __restrict__ Ws,     // [64, 5, 5]
    const float* __restrict__ bs,     // [64, 5]
    const float* __restrict__ W_out,  // [1, 5]
    const float* __restrict__ b_out,  // [1]
    float* __restrict__ out,          // [n]
    int n)
{
    const int row = blockIdx.x * blockDim.x + threadIdx.x;
    if (row >= n) return;

    float h[MLP_D];
    const float* xr = x + (long)row * MLP_D;
#pragma unroll
    for (int i = 0; i < MLP_D; ++i) h[i] = xr[i];

    for (int l = 0; l < MLP_DEPTH; ++l) {
        const float* W = Ws + l * (MLP_D * MLP_D);  // wave-uniform address
        const float* b = bs + l * MLP_D;            // wave-uniform address
        float nh[MLP_D];
#pragma unroll
        for (int j = 0; j < MLP_D; ++j) {
            float acc = b[j];
#pragma unroll
            for (int i = 0; i < MLP_D; ++i)
                acc = fmaf(h[i], W[j * MLP_D + i], acc);  // h@W.T
            nh[j] = fmaxf(acc, 0.0f);                      // ReLU
        }
#pragma unroll
        for (int j = 0; j < MLP_D; ++j) h[j] = nh[j];
    }

    float acc = b_out[0];
#pragma unroll
    for (int i = 0; i < MLP_D; ++i) acc = fmaf(h[i], W_out[i], acc);
    out[row] = acc;
}

extern "C" void kernel_launch(void* const* d_in, const int* in_sizes, int n_in,
                              void* d_out, int out_size, void* d_ws, size_t ws_size,
                              hipStream_t stream) {
    const float* x     = (const float*)d_in[0];
    const float* Ws    = (const float*)d_in[1];
    const float* bs    = (const float*)d_in[2];
    const float* W_out = (const float*)d_in[3];
    const float* b_out = (const float*)d_in[4];
    float* out = (float*)d_out;

    const int n = in_sizes[0] / MLP_D;  // batch rows
    const int block = 256;
    const int grid = (n + block - 1) / block;
    MLP_89687507075104_kernel<<<grid, block, 0, stream>>>(
        x, Ws, bs, W_out, b_out, out, n);
}

// Round 2
// 119.708 us; speedup vs baseline: 1.0747x; 1.0747x over previous
//
#include <hip/hip_runtime.h>

// MLP: 64 × (Linear(5,5)+ReLU) then Linear(5,1), BATCH = 1048576 rows.
// fp32 VALU compute-bound (no fp32 MFMA on CDNA4; D=5 too small for MFMA
// tiles anyway). One thread per row, h[5] in VGPRs.
//
// R2 changes vs R1 (66 µs):
//  - FULL UNROLL of the 64-layer loop: kills the nh->h register copy
//    (SSA renaming) and lets the scheduler hoist next layers' s_load of
//    weights ahead of current FMAs (hides scalar-cache latency).
//  - Biases staged in LDS (padded to 8 floats/layer for 16B-aligned
//    float4 reads, broadcast = conflict-free): bias lands in a VGPR so
//    the first fma uses it as addend directly -> removes 5 v_mov/layer
//    (fma can't take weight SGPR + bias SGPR in one instr).
//  - Weights stay wave-uniform global loads -> s_load, feeding v_fma_f32
//    as its single allowed SGPR operand (zero VALU cost for weights).

#define MLP_DEPTH 64
#define MLP_D 5

__global__ __launch_bounds__(256) void MLP_89687507075104_kernel(
    const float* __restrict__ x,      // [n, 5]
    const float* __restrict__ Ws,     // [64, 5, 5]
    const float* __restrict__ bs,     // [64, 5]
    const float* __restrict__ W_out,  // [1, 5]
    const float* __restrict__ b_out,  // [1]
    float* __restrict__ out,          // [n]
    int n)
{
    // Biases in LDS, padded stride 8 for aligned float4 + float reads.
    __shared__ float sb[MLP_DEPTH * 8];
    for (int i = threadIdx.x; i < MLP_DEPTH * MLP_D; i += 256) {
        sb[(i / MLP_D) * 8 + (i % MLP_D)] = bs[i];
    }
    __syncthreads();

    const int row = blockIdx.x * blockDim.x + threadIdx.x;
    if (row >= n) return;

    const float* xr = x + (long)row * MLP_D;
    float h[MLP_D];
#pragma unroll
    for (int i = 0; i < MLP_D; ++i) h[i] = xr[i];

#pragma unroll
    for (int l = 0; l < MLP_DEPTH; ++l) {
        const float* W = Ws + l * (MLP_D * MLP_D);  // wave-uniform, const offsets
        const float4 b4 = *reinterpret_cast<const float4*>(&sb[l * 8]);
        float a0 = b4.x, a1 = b4.y, a2 = b4.z, a3 = b4.w;
        float a4 = sb[l * 8 + 4];
#pragma unroll
        for (int i = 0; i < MLP_D; ++i) {
            a0 = fmaf(h[i], W[0 * MLP_D + i], a0);
            a1 = fmaf(h[i], W[1 * MLP_D + i], a1);
            a2 = fmaf(h[i], W[2 * MLP_D + i], a2);
            a3 = fmaf(h[i], W[3 * MLP_D + i], a3);
            a4 = fmaf(h[i], W[4 * MLP_D + i], a4);
        }
        h[0] = fmaxf(a0, 0.0f);
        h[1] = fmaxf(a1, 0.0f);
        h[2] = fmaxf(a2, 0.0f);
        h[3] = fmaxf(a3, 0.0f);
        h[4] = fmaxf(a4, 0.0f);
    }

    float acc = b_out[0];
#pragma unroll
    for (int i = 0; i < MLP_D; ++i) acc = fmaf(h[i], W_out[i], acc);
    out[row] = acc;
}

extern "C" void kernel_launch(void* const* d_in, const int* in_sizes, int n_in,
                              void* d_out, int out_size, void* d_ws, size_t ws_size,
                              hipStream_t stream) {
    const float* x     = (const float*)d_in[0];
    const float* Ws    = (const float*)d_in[1];
    const float* bs    = (const float*)d_in[2];
    const float* W_out = (const float*)d_in[3];
    const float* b_out = (const float*)d_in[4];
    float* out = (float*)d_out;

    const int n = in_sizes[0] / MLP_D;  // batch rows
    const int block = 256;
    const int grid = (n + block - 1) / block;
    MLP_89687507075104_kernel<<<grid, block, 0, stream>>>(
        x, Ws, bs, W_out, b_out, out, n);
}

// Round 3
// 110.336 us; speedup vs baseline: 1.1660x; 1.0849x over previous
//
#include <hip/hip_runtime.h>

// MLP: 64 × (Linear(5,5)+ReLU) then Linear(5,1), BATCH = 1048576 rows.
// fp32 VALU compute-bound. R3 strategy: packed fp32 (v_pk_fma_f32) with
// TWO BATCH ROWS per float2 lane-pair, 4 rows per thread:
//  - h/acc are natural VGPR pairs (no splat of activations needed)
//  - only the wave-uniform weight is splat (op_sel fold, or 1 mov
//    amortized over 4 rows)
//  - 70 VALU instr per layer per 4 rows = 17.5/row vs ~56/row in R2
//  - x: rows 4t..4t+3 are 20 contiguous floats -> 5x dwordx4, coalesced
//  - out: 4 contiguous floats -> 1x dwordx4

#define MLP_DEPTH 64
#define MLP_D 5
#define ROWS_PER_THREAD 4  // 2 float2 pairs

typedef float f2 __attribute__((ext_vector_type(2)));

__global__ __launch_bounds__(256) void MLP_89687507075104_kernel(
    const float* __restrict__ x,      // [n, 5]
    const float* __restrict__ Ws,     // [64, 5, 5]
    const float* __restrict__ bs,     // [64, 5]
    const float* __restrict__ W_out,  // [1, 5]
    const float* __restrict__ b_out,  // [1]
    float* __restrict__ out,          // [n]
    int n)
{
    const int t = blockIdx.x * blockDim.x + threadIdx.x;
    const long row0 = (long)t * ROWS_PER_THREAD;
    if (row0 >= n) return;

    // Load 20 contiguous floats = rows 4t..4t+3 (16B-aligned: 80B/thread).
    float f[ROWS_PER_THREAD * MLP_D];
    const float4* xp = reinterpret_cast<const float4*>(x + row0 * MLP_D);
#pragma unroll
    for (int q = 0; q < 5; ++q) {
        const float4 v = xp[q];
        f[4 * q + 0] = v.x; f[4 * q + 1] = v.y;
        f[4 * q + 2] = v.z; f[4 * q + 3] = v.w;
    }

    // h[p][i] = element i of (row 2p, row 2p+1) packed in a float2.
    f2 h[2][MLP_D];
#pragma unroll
    for (int i = 0; i < MLP_D; ++i) {
        h[0][i] = (f2){ f[0 * MLP_D + i], f[1 * MLP_D + i] };
        h[1][i] = (f2){ f[2 * MLP_D + i], f[3 * MLP_D + i] };
    }

#pragma unroll
    for (int l = 0; l < MLP_DEPTH; ++l) {
        const float* W = Ws + l * (MLP_D * MLP_D);  // wave-uniform
        const float* b = bs + l * MLP_D;            // wave-uniform
        f2 a[2][MLP_D];
#pragma unroll
        for (int j = 0; j < MLP_D; ++j) {
            const float w0 = W[j * MLP_D + 0];
            a[0][j] = h[0][0] * w0;            // v_pk_mul_f32
            a[1][j] = h[1][0] * w0;
#pragma unroll
            for (int i = 1; i < MLP_D; ++i) {
                const float w = W[j * MLP_D + i];
                a[0][j] += h[0][i] * w;        // v_pk_fma_f32
                a[1][j] += h[1][i] * w;
            }
            const float bj = b[j];
            a[0][j] += bj;                     // v_pk_add_f32 (splat)
            a[1][j] += bj;
        }
#pragma unroll
        for (int j = 0; j < MLP_D; ++j) {
            h[0][j] = __builtin_elementwise_max(a[0][j], (f2)0.0f);  // v_pk_max_f32
            h[1][j] = __builtin_elementwise_max(a[1][j], (f2)0.0f);
        }
    }

    // Output layer: Linear(5,1).
    const float bo = b_out[0];
    f2 o0 = (f2)bo, o1 = (f2)bo;
#pragma unroll
    for (int i = 0; i < MLP_D; ++i) {
        const float w = W_out[i];
        o0 += h[0][i] * w;
        o1 += h[1][i] * w;
    }
    float4 ov;
    ov.x = o0[0]; ov.y = o0[1]; ov.z = o1[0]; ov.w = o1[1];
    *reinterpret_cast<float4*>(out + row0) = ov;
}

extern "C" void kernel_launch(void* const* d_in, const int* in_sizes, int n_in,
                              void* d_out, int out_size, void* d_ws, size_t ws_size,
                              hipStream_t stream) {
    const float* x     = (const float*)d_in[0];
    const float* Ws    = (const float*)d_in[1];
    const float* bs    = (const float*)d_in[2];
    const float* W_out = (const float*)d_in[3];
    const float* b_out = (const float*)d_in[4];
    float* out = (float*)d_out;

    const int n = in_sizes[0] / MLP_D;  // batch rows (1048576)
    const int block = 256;
    const int threads_needed = (n + ROWS_PER_THREAD - 1) / ROWS_PER_THREAD;
    const int grid = (threads_needed + block - 1) / block;
    MLP_89687507075104_kernel<<<grid, block, 0, stream>>>(
        x, Ws, bs, W_out, b_out, out, n);
}